// Round 1
// baseline (1882.064 us; speedup 1.0000x reference)
//
#include <hip/hip_runtime.h>
#include <hip/hip_bf16.h>
#include <math.h>

// Problem constants (from reference): B=2, T=2048, C=1024, H=16, D=64
#define BB 2
#define TT 2048
#define CC 1024
#define HH 16
#define DD 64
#define MM (BB*TT)              // 4096 rows in token-major GEMMs
#define ATT_SCALE 0.125f        // 1/sqrt(64)
#define N_ROWS_TOTAL (BB*HH*TT) // 65536 rows for entropy mean

// ---------------------------------------------------------------------------
// Shared 128x128 fp32 GEMM body: C[m][n] = sum_k A[m][k] * Wt[n][k]  (+bias
// pre-loaded into acc by caller).  256 threads as 16x16, 8x8 micro-tile split
// into 2x2 blocks of 4x4 (rows: half*64 + ty*4 + i, cols: half*64 + tx*4 + j).
// ---------------------------------------------------------------------------
__device__ __forceinline__ void gemm128_body(
    const float* __restrict__ A, const float* __restrict__ Wt,
    int m0, int n0, float acc[8][8],
    float (*As)[20], float (*Bs)[20], int tx, int ty, int tid)
{
    for (int k0 = 0; k0 < CC; k0 += 16) {
        __syncthreads();
        // stage A tile [128][16] and W tile [128][16] (natural layout, float4)
        int idx = tid;
#pragma unroll
        for (int s2 = 0; s2 < 2; ++s2, idx += 256) {
            int row  = idx >> 2;
            int kseg = (idx & 3) << 2;
            *(float4*)&As[row][kseg] =
                *(const float4*)&A[(size_t)(m0 + row) * CC + k0 + kseg];
            *(float4*)&Bs[row][kseg] =
                *(const float4*)&Wt[(size_t)(n0 + row) * CC + k0 + kseg];
        }
        __syncthreads();
#pragma unroll
        for (int k4 = 0; k4 < 4; ++k4) {
            float4 a[8], b[8];
#pragma unroll
            for (int h2 = 0; h2 < 2; ++h2)
#pragma unroll
                for (int i = 0; i < 4; ++i) {
                    a[h2 * 4 + i] = *(float4*)&As[h2 * 64 + ty * 4 + i][k4 * 4];
                    b[h2 * 4 + i] = *(float4*)&Bs[h2 * 64 + tx * 4 + i][k4 * 4];
                }
#pragma unroll
            for (int ii = 0; ii < 8; ++ii)
#pragma unroll
                for (int jj = 0; jj < 8; ++jj) {
                    acc[ii][jj] += a[ii].x * b[jj].x;
                    acc[ii][jj] += a[ii].y * b[jj].y;
                    acc[ii][jj] += a[ii].z * b[jj].z;
                    acc[ii][jj] += a[ii].w * b[jj].w;
                }
        }
    }
}

// ---------------------------------------------------------------------------
// Kernel 1: fused QKV projection. grid = (24, 32): x = n-block (which matrix +
// column block), y = m-block. Output scattered to [B,H,T,D].
// ---------------------------------------------------------------------------
__global__ __launch_bounds__(256)
void qkv_gemm_kernel(const float* __restrict__ X,
                     const float* __restrict__ wq, const float* __restrict__ bq,
                     const float* __restrict__ wk, const float* __restrict__ bk,
                     const float* __restrict__ wv, const float* __restrict__ bv,
                     float* __restrict__ Qo, float* __restrict__ Ko,
                     float* __restrict__ Vo)
{
    __shared__ float As[128][20];
    __shared__ float Bs[128][20];
    const int tid = threadIdx.x;
    const int tx = tid & 15, ty = tid >> 4;
    const int nb = blockIdx.x;          // 0..23
    const int mb = blockIdx.y;          // 0..31
    const int which = nb >> 3;          // 0=q, 1=k, 2=v
    const int nloc  = (nb & 7) * 128;   // column block within [0,1024)
    const float* W    = (which == 0) ? wq : (which == 1) ? wk : wv;
    const float* bias = (which == 0) ? bq : (which == 1) ? bk : bv;
    float* Out        = (which == 0) ? Qo : (which == 1) ? Ko : Vo;
    const int m0 = mb * 128;

    float4 bv0 = *(const float4*)&bias[nloc + tx * 4];
    float4 bv1 = *(const float4*)&bias[nloc + 64 + tx * 4];
    float acc[8][8];
#pragma unroll
    for (int ii = 0; ii < 8; ++ii) {
        acc[ii][0] = bv0.x; acc[ii][1] = bv0.y; acc[ii][2] = bv0.z; acc[ii][3] = bv0.w;
        acc[ii][4] = bv1.x; acc[ii][5] = bv1.y; acc[ii][6] = bv1.z; acc[ii][7] = bv1.w;
    }

    gemm128_body(X, W, m0, nloc, acc, As, Bs, tx, ty, tid);

    // scatter to [B,H,T,D]
#pragma unroll
    for (int rh = 0; rh < 2; ++rh)
#pragma unroll
        for (int i = 0; i < 4; ++i) {
            int m = m0 + rh * 64 + ty * 4 + i;
            int b = m >> 11;        // m / T
            int t = m & 2047;       // m % T
#pragma unroll
            for (int ch = 0; ch < 2; ++ch) {
                int h = (nloc >> 6) + ch;
                float4 o;
                o.x = acc[rh * 4 + i][ch * 4 + 0];
                o.y = acc[rh * 4 + i][ch * 4 + 1];
                o.z = acc[rh * 4 + i][ch * 4 + 2];
                o.w = acc[rh * 4 + i][ch * 4 + 3];
                *(float4*)&Out[(((size_t)b * HH + h) * TT + t) * DD + tx * 4] = o;
            }
        }
}

// ---------------------------------------------------------------------------
// Kernel 2: causal flash attention + online entropy statistic.
// grid = (T/64 = 32, B*H = 32). Block 256 threads = 16x16; each thread owns a
// 4x4 micro-tile with the SAME row mapping for QK^T and PV, so online-softmax
// state (m, l, E) lives in registers, reduced across the 16 tx-lanes via shfl.
// ---------------------------------------------------------------------------
__global__ __launch_bounds__(256)
void attn_kernel(const float* __restrict__ Q, const float* __restrict__ K,
                 const float* __restrict__ V, float* __restrict__ Att,
                 float* __restrict__ Ent)
{
    __shared__ float Qs[64][68];
    __shared__ float Ks[64][68];
    __shared__ float Vs[64][68];
    __shared__ float Ps[64][68];
    __shared__ float wred[4];

    const int tid = threadIdx.x;
    const int tx = tid & 15, ty = tid >> 4;
    const int qt = blockIdx.x;          // Q row-tile index
    const int bh = blockIdx.y;          // b*H + h
    const int b  = bh >> 4, h = bh & 15;
    const int q0 = qt * 64;

    const float* Qb = Q + (size_t)bh * TT * DD;
    const float* Kb = K + (size_t)bh * TT * DD;
    const float* Vb = V + (size_t)bh * TT * DD;

    // stage Q tile once: [64][64] natural layout
#pragma unroll
    for (int s2 = 0; s2 < 4; ++s2) {
        int idx = tid + s2 * 256;
        int row = idx >> 4;
        int seg = (idx & 15) << 2;
        *(float4*)&Qs[row][seg] =
            *(const float4*)&Qb[(size_t)(q0 + row) * DD + seg];
    }

    float m_[4], l_[4], E_[4], acc[4][4];
#pragma unroll
    for (int i = 0; i < 4; ++i) {
        m_[i] = -3.0e38f; l_[i] = 0.f; E_[i] = 0.f;
#pragma unroll
        for (int j = 0; j < 4; ++j) acc[i][j] = 0.f;
    }

    for (int kt = 0; kt <= qt; ++kt) {
        __syncthreads();   // protect Ks/Vs/Ps (and first-iter Qs) readers
        // stage K,V tiles
#pragma unroll
        for (int s2 = 0; s2 < 4; ++s2) {
            int idx = tid + s2 * 256;
            int row = idx >> 4;
            int seg = (idx & 15) << 2;
            *(float4*)&Ks[row][seg] =
                *(const float4*)&Kb[(size_t)(kt * 64 + row) * DD + seg];
            *(float4*)&Vs[row][seg] =
                *(const float4*)&Vb[(size_t)(kt * 64 + row) * DD + seg];
        }
        __syncthreads();

        // ---- scores: s[i][j] = Q[r_i] . K[c_j] ----
        float s[4][4];
#pragma unroll
        for (int i = 0; i < 4; ++i)
#pragma unroll
            for (int j = 0; j < 4; ++j) s[i][j] = 0.f;
#pragma unroll
        for (int d4 = 0; d4 < 16; ++d4) {
            float4 qr[4], kc[4];
#pragma unroll
            for (int i = 0; i < 4; ++i)
                qr[i] = *(float4*)&Qs[ty * 4 + i][d4 * 4];
#pragma unroll
            for (int j = 0; j < 4; ++j)
                kc[j] = *(float4*)&Ks[tx * 4 + j][d4 * 4];
#pragma unroll
            for (int i = 0; i < 4; ++i)
#pragma unroll
                for (int j = 0; j < 4; ++j) {
                    s[i][j] += qr[i].x * kc[j].x;
                    s[i][j] += qr[i].y * kc[j].y;
                    s[i][j] += qr[i].z * kc[j].z;
                    s[i][j] += qr[i].w * kc[j].w;
                }
        }
        // scale + causal mask (only diagonal tile has masked entries)
        const bool diag = (kt == qt);
#pragma unroll
        for (int i = 0; i < 4; ++i) {
            int rg = q0 + ty * 4 + i;
#pragma unroll
            for (int j = 0; j < 4; ++j) {
                s[i][j] *= ATT_SCALE;
                int cg = kt * 64 + tx * 4 + j;
                if (diag && cg > rg) s[i][j] = -1.0e30f;  // exp -> 0 exactly
            }
        }

        // ---- online softmax update per row (reduce across 16 tx lanes) ----
#pragma unroll
        for (int i = 0; i < 4; ++i) {
            float mt = fmaxf(fmaxf(s[i][0], s[i][1]), fmaxf(s[i][2], s[i][3]));
#pragma unroll
            for (int off = 1; off < 16; off <<= 1)
                mt = fmaxf(mt, __shfl_xor(mt, off));
            float mnew = fmaxf(m_[i], mt);
            float f = expf(m_[i] - mnew);      // 0 on first tile (m_=-3e38)
            float pt[4];
            float lt = 0.f, Et = 0.f;
#pragma unroll
            for (int j = 0; j < 4; ++j) {
                pt[j] = expf(s[i][j] - mnew);  // masked: exp(huge neg) == 0
                lt += pt[j];
                Et += pt[j] * s[i][j];         // 0 * -1e30 == -0, no NaN
            }
#pragma unroll
            for (int off = 1; off < 16; off <<= 1) {
                lt += __shfl_xor(lt, off);
                Et += __shfl_xor(Et, off);
            }
            l_[i] = l_[i] * f + lt;
            E_[i] = E_[i] * f + Et;
            m_[i] = mnew;
#pragma unroll
            for (int j = 0; j < 4; ++j) acc[i][j] *= f;
            // stash unnormalized probs: Ps[row][col]
            float4 pv4; pv4.x = pt[0]; pv4.y = pt[1]; pv4.z = pt[2]; pv4.w = pt[3];
            *(float4*)&Ps[ty * 4 + i][tx * 4] = pv4;
        }
        __syncthreads();

        // ---- PV: acc[i][j] += sum_c P[r_i][c] * V[c][d_j] ----
#pragma unroll
        for (int c4 = 0; c4 < 16; ++c4) {
            float4 pr[4], vc[4];
#pragma unroll
            for (int i = 0; i < 4; ++i)
                pr[i] = *(float4*)&Ps[ty * 4 + i][c4 * 4];
#pragma unroll
            for (int q = 0; q < 4; ++q)
                vc[q] = *(float4*)&Vs[c4 * 4 + q][tx * 4];
#pragma unroll
            for (int i = 0; i < 4; ++i)
#pragma unroll
                for (int j = 0; j < 4; ++j) {
                    acc[i][j] += pr[i].x * (&vc[0].x)[j];
                    acc[i][j] += pr[i].y * (&vc[1].x)[j];
                    acc[i][j] += pr[i].z * (&vc[2].x)[j];
                    acc[i][j] += pr[i].w * (&vc[3].x)[j];
                }
        }
    }

    // ---- epilogue: normalize, write att in [B,T,C]; entropy reduce ----
    float hsum = 0.f;
#pragma unroll
    for (int i = 0; i < 4; ++i) {
        float invl = 1.0f / l_[i];
        float4 o;
        o.x = acc[i][0] * invl; o.y = acc[i][1] * invl;
        o.z = acc[i][2] * invl; o.w = acc[i][3] * invl;
        int t = q0 + ty * 4 + i;
        *(float4*)&Att[((size_t)b * TT + t) * CC + h * DD + tx * 4] = o;
        // per-row entropy: m + log(l) - E/l  ==  -sum p log p
        hsum += m_[i] + logf(l_[i]) - E_[i] * invl;
    }
    hsum = (tx == 0) ? hsum : 0.f;   // one contributor per row
#pragma unroll
    for (int off = 1; off < 64; off <<= 1) hsum += __shfl_xor(hsum, off);
    if ((tid & 63) == 0) wred[tid >> 6] = hsum;
    __syncthreads();
    if (tid == 0) {
        float blocksum = wred[0] + wred[1] + wred[2] + wred[3];
        atomicAdd(Ent, blocksum * (1.0f / (float)N_ROWS_TOTAL));
    }
}

// ---------------------------------------------------------------------------
// Kernel 3: output projection out = att @ wo^T + bo, written to d_out [B,T,C].
// grid = (8, 32).
// ---------------------------------------------------------------------------
__global__ __launch_bounds__(256)
void out_proj_kernel(const float* __restrict__ AttIn,
                     const float* __restrict__ wo, const float* __restrict__ bo,
                     float* __restrict__ Out)
{
    __shared__ float As[128][20];
    __shared__ float Bs[128][20];
    const int tid = threadIdx.x;
    const int tx = tid & 15, ty = tid >> 4;
    const int n0 = blockIdx.x * 128;
    const int m0 = blockIdx.y * 128;

    float4 bv0 = *(const float4*)&bo[n0 + tx * 4];
    float4 bv1 = *(const float4*)&bo[n0 + 64 + tx * 4];
    float acc[8][8];
#pragma unroll
    for (int ii = 0; ii < 8; ++ii) {
        acc[ii][0] = bv0.x; acc[ii][1] = bv0.y; acc[ii][2] = bv0.z; acc[ii][3] = bv0.w;
        acc[ii][4] = bv1.x; acc[ii][5] = bv1.y; acc[ii][6] = bv1.z; acc[ii][7] = bv1.w;
    }

    gemm128_body(AttIn, wo, m0, n0, acc, As, Bs, tx, ty, tid);

#pragma unroll
    for (int rh = 0; rh < 2; ++rh)
#pragma unroll
        for (int i = 0; i < 4; ++i) {
            int m = m0 + rh * 64 + ty * 4 + i;
#pragma unroll
            for (int ch = 0; ch < 2; ++ch) {
                float4 o;
                o.x = acc[rh * 4 + i][ch * 4 + 0];
                o.y = acc[rh * 4 + i][ch * 4 + 1];
                o.z = acc[rh * 4 + i][ch * 4 + 2];
                o.w = acc[rh * 4 + i][ch * 4 + 3];
                *(float4*)&Out[(size_t)m * CC + n0 + ch * 64 + tx * 4] = o;
            }
        }
}

__global__ void zero_ent_kernel(float* __restrict__ e) { *e = 0.f; }

// ---------------------------------------------------------------------------
extern "C" void kernel_launch(void* const* d_in, const int* in_sizes, int n_in,
                              void* d_out, int out_size, void* d_ws, size_t ws_size,
                              hipStream_t stream)
{
    const float* x  = (const float*)d_in[0];
    // d_in[1] = causal mask (tril) — structure is known, not read on device
    const float* wq = (const float*)d_in[2];
    const float* bq = (const float*)d_in[3];
    const float* wk = (const float*)d_in[4];
    const float* bk = (const float*)d_in[5];
    const float* wv = (const float*)d_in[6];
    const float* bv = (const float*)d_in[7];
    const float* wo = (const float*)d_in[8];
    const float* bo = (const float*)d_in[9];

    float* out = (float*)d_out;
    float* ent = out + (size_t)BB * TT * CC;   // scalar appended after out

    const size_t NELT = (size_t)BB * HH * TT * DD;  // 4,194,304 per tensor
    float* Qw  = (float*)d_ws;
    float* Kw  = Qw + NELT;
    float* Vw  = Kw + NELT;
    float* Att = Vw + NELT;

    zero_ent_kernel<<<1, 1, 0, stream>>>(ent);
    qkv_gemm_kernel<<<dim3(24, 32), 256, 0, stream>>>(
        x, wq, bq, wk, bk, wv, bv, Qw, Kw, Vw);
    attn_kernel<<<dim3(32, 32), 256, 0, stream>>>(Qw, Kw, Vw, Att, ent);
    out_proj_kernel<<<dim3(8, 32), 256, 0, stream>>>(Att, wo, bo, out);
}

// Round 2
// 316.794 us; speedup vs baseline: 5.9410x; 5.9410x over previous
//
#include <hip/hip_runtime.h>
#include <math.h>

// B=2, T=2048, C=1024, H=16, D=64
typedef short bf8_t __attribute__((ext_vector_type(8)));   // 8 bf16 (4 VGPR)
typedef float f4_t  __attribute__((ext_vector_type(4)));
typedef unsigned int u32;
typedef unsigned short u16;

#define MFMA(a,b,c) __builtin_amdgcn_mfma_f32_16x16x32_bf16((a),(b),(c),0,0,0)

__device__ __forceinline__ void gload16(const void* g, void* l) {
  __builtin_amdgcn_global_load_lds(
      (const __attribute__((address_space(1))) void*)g,
      (__attribute__((address_space(3))) void*)l, 16, 0, 0);
}

__device__ __forceinline__ u16 f2bf(float f) {   // RNE truncate f32->bf16
  u32 u = __float_as_uint(f);
  u += 0x7fff + ((u >> 16) & 1);
  return (u16)(u >> 16);
}

// ---------------------------------------------------------------------------
// Shared 128x128 bf16-MFMA tile: acc += A[m0..][k] * B[n0..][k]^T (both row-
// major [rows][K]). 256 thr / 4 waves (2x2 of 64x64). BK=64. LDS [row][64]
// with 16B-granule XOR swizzle: phys_granule = logical ^ (row&7); staged via
// global_load_lds (linear dest + inverse-swizzled global source, rule #21).
// ---------------------------------------------------------------------------
__device__ __forceinline__ void gemm_tile(
    const u16* __restrict__ A, const u16* __restrict__ Bm,
    int lda, int ldb, int m0, int n0, int K,
    short* As, short* Bs, f4_t acc[4][4], int tid)
{
  const int lane = tid & 63, w = tid >> 6;
  const int lo = lane & 15, hi = lane >> 4;
  const int wr = (w >> 1) * 64, wc = (w & 1) * 64;
  for (int k0 = 0; k0 < K; k0 += 64) {
    __syncthreads();
#pragma unroll
    for (int iss = 0; iss < 4; ++iss) {
      int bb = iss * 4096 + tid * 16;          // linear LDS byte
      int row = bb >> 7;                       // 128 B per row
      int lg = ((bb >> 4) & 7) ^ (row & 7);    // inverse-swizzled src granule
      gload16(A  + (size_t)(m0 + row) * lda + k0 + lg * 8,
              (char*)As + iss * 4096 + w * 1024);
      gload16(Bm + (size_t)(n0 + row) * ldb + k0 + lg * 8,
              (char*)Bs + iss * 4096 + w * 1024);
    }
    __syncthreads();
#pragma unroll
    for (int kk = 0; kk < 2; ++kk) {
      bf8_t af[4], bfr[4];
#pragma unroll
      for (int m = 0; m < 4; ++m) {
        int row = wr + m * 16 + lo;
        int g = (kk * 4 + hi) ^ (row & 7);
        af[m] = *(const bf8_t*)&As[row * 64 + g * 8];
      }
#pragma unroll
      for (int n = 0; n < 4; ++n) {
        int row = wc + n * 16 + lo;
        int g = (kk * 4 + hi) ^ (row & 7);
        bfr[n] = *(const bf8_t*)&Bs[row * 64 + g * 8];
      }
#pragma unroll
      for (int m = 0; m < 4; ++m)
#pragma unroll
        for (int n = 0; n < 4; ++n)
          acc[m][n] = MFMA(af[m], bfr[n], acc[m][n]);
    }
  }
}

// ---------------------------------------------------------------------------
// K1: convert fp32 inputs -> bf16 workspace copies; zero entropy scalar.
// ---------------------------------------------------------------------------
__global__ __launch_bounds__(256)
void convert_kernel(const float* __restrict__ x,  const float* __restrict__ wq,
                    const float* __restrict__ wk, const float* __restrict__ wv,
                    const float* __restrict__ wo,
                    u16* xb, u16* wqb, u16* wkb, u16* wvb, u16* wob, float* ent)
{
  size_t i = (size_t)blockIdx.x * 256 + threadIdx.x;   // chunk of 8 elems
  if (blockIdx.x == 0 && threadIdx.x == 0) *ent = 0.f;
  const float* src; u16* dst; size_t off;
  if (i < 524288) { src = x; dst = xb; off = i; }
  else {
    size_t r = i - 524288;
    int sel = (int)(r >> 17);
    off = r & 131071;
    src = sel == 0 ? wq : sel == 1 ? wk : sel == 2 ? wv : wo;
    dst = sel == 0 ? wqb : sel == 1 ? wkb : sel == 2 ? wvb : wob;
  }
  f4_t a = *(const f4_t*)&src[off * 8];
  f4_t c = *(const f4_t*)&src[off * 8 + 4];
  u16 t[8] = {f2bf(a[0]), f2bf(a[1]), f2bf(a[2]), f2bf(a[3]),
              f2bf(c[0]), f2bf(c[1]), f2bf(c[2]), f2bf(c[3])};
  *(uint4*)&dst[off * 8] = *(const uint4*)t;
}

// ---------------------------------------------------------------------------
// K2: fused QKV projection (bf16 MFMA), scatter to [B,H,T,D] in bf16.
// grid = (24, 32): x = {matrix, col-block}, y = row-block.
// ---------------------------------------------------------------------------
__global__ __launch_bounds__(256)
void qkv_kernel(const u16* __restrict__ X, const u16* __restrict__ Wq,
                const u16* __restrict__ Wk, const u16* __restrict__ Wv,
                const float* __restrict__ bq, const float* __restrict__ bk,
                const float* __restrict__ bv,
                u16* Qo, u16* Ko, u16* Vo)
{
  __shared__ short As[8192], Bs[8192];
  const int tid = threadIdx.x;
  const int nb = blockIdx.x;
  const int which = nb >> 3;
  const int n0 = (nb & 7) * 128;
  const int m0 = blockIdx.y * 128;
  const u16* W    = which == 0 ? Wq : which == 1 ? Wk : Wv;
  const float* bias = which == 0 ? bq : which == 1 ? bk : bv;
  u16* Out        = which == 0 ? Qo : which == 1 ? Ko : Vo;

  f4_t acc[4][4];
#pragma unroll
  for (int m = 0; m < 4; ++m)
#pragma unroll
    for (int n = 0; n < 4; ++n) acc[m][n] = f4_t{0.f, 0.f, 0.f, 0.f};

  gemm_tile(X, W, 1024, 1024, m0, n0, 1024, As, Bs, acc, tid);

  const int lane = tid & 63, w = tid >> 6;
  const int lo = lane & 15, hi = lane >> 4;
  const int wr = (w >> 1) * 64, wc = (w & 1) * 64;
#pragma unroll
  for (int n = 0; n < 4; ++n) {
    int col = n0 + wc + n * 16 + lo;
    float bb = bias[col];
    int hh = col >> 6, d = col & 63;
#pragma unroll
    for (int m = 0; m < 4; ++m)
#pragma unroll
      for (int j = 0; j < 4; ++j) {
        int row = m0 + wr + m * 16 + hi * 4 + j;
        int bidx = row >> 11, t = row & 2047;
        Out[(((size_t)bidx * 16 + hh) * 2048 + t) * 64 + d] =
            f2bf(acc[m][n][j] + bb);
      }
  }
}

// ---------------------------------------------------------------------------
// K3: causal flash attention + online entropy, bf16 MFMA.
// grid = (16, 32): 128 Q-rows per block, 4 waves x 32 rows; KV tiles of 64.
// QK^T computed swapped (mfma(K,Q)) and PV swapped (mfma(V^T,P^T)) so the
// softmax state and output columns are lane-local (q = w*32 + nq*16 + lane&15).
// ---------------------------------------------------------------------------
__global__ __launch_bounds__(256)
void attn_kernel(const u16* __restrict__ Qg, const u16* __restrict__ Kg,
                 const u16* __restrict__ Vg, u16* __restrict__ Att,
                 float* __restrict__ Ent)
{
  __shared__ char smem[32768];
  __shared__ float wred[4];
  short* Ks = (short*)smem;                // [64 kv][64 d]  swz(row&7)
  short* Vt = (short*)(smem + 8192);       // [64 d][64 kv]  swz(row&7)
  short* Ps = (short*)(smem + 16384);      // [128 q][64 kv] swz(row&7)

  const int tid = threadIdx.x, lane = tid & 63, w = tid >> 6;
  const int lo = lane & 15, hi = lane >> 4;
  const int qt = blockIdx.x, bh = blockIdx.y;
  const int b = bh >> 4, h = bh & 15;
  const int q0 = qt * 128;
  const u16* Qb = Qg + (size_t)bh * (2048 * 64);
  const u16* Kb = Kg + (size_t)bh * (2048 * 64);
  const u16* Vb = Vg + (size_t)bh * (2048 * 64);

  // Q as B-operand frags: B[d][q], lane: q = w*32+nq*16+lo, d = kk*32+hi*8+j
  bf8_t qf[2][2];
#pragma unroll
  for (int nq = 0; nq < 2; ++nq)
#pragma unroll
    for (int kk = 0; kk < 2; ++kk) {
      int row = q0 + w * 32 + nq * 16 + lo;
      qf[nq][kk] = *(const bf8_t*)&Qb[(size_t)row * 64 + kk * 32 + hi * 8];
    }

  f4_t o[4][2];                 // o[md][nq][j] = out[d=md*16+hi*4+j][q(nq,lo)]
  float m_[2], l_[2], E_[2];
#pragma unroll
  for (int md = 0; md < 4; ++md)
#pragma unroll
    for (int nq = 0; nq < 2; ++nq) o[md][nq] = f4_t{0.f, 0.f, 0.f, 0.f};
#pragma unroll
  for (int nq = 0; nq < 2; ++nq) { m_[nq] = -3.0e38f; l_[nq] = 0.f; E_[nq] = 0.f; }

  const int ntile = 2 * qt + 2;
  for (int kt = 0; kt < ntile; ++kt) {
    __syncthreads();
    // stage K (global_load_lds, swizzled)
#pragma unroll
    for (int iss = 0; iss < 2; ++iss) {
      int bb = iss * 4096 + tid * 16;
      int row = bb >> 7;
      int lg = ((bb >> 4) & 7) ^ (row & 7);
      gload16(Kb + (size_t)(kt * 64 + row) * 64 + lg * 8,
              smem + iss * 4096 + w * 1024);
    }
    // stage V transposed (reg path: coalesced load, scalar LDS writes)
#pragma unroll
    for (int rep = 0; rep < 2; ++rep) {
      int idx = rep * 256 + tid;
      int r = idx >> 3, seg = idx & 7;
      bf8_t vv = *(const bf8_t*)&Vb[(size_t)(kt * 64 + r) * 64 + seg * 8];
#pragma unroll
      for (int jj = 0; jj < 8; ++jj) {
        int d = seg * 8 + jj;
        Vt[d * 64 + (((r >> 3) ^ (d & 7)) << 3) + (r & 7)] = vv[jj];
      }
    }
    __syncthreads();

    // S' = K·Q^T : s[mk][nq][j] at kv = kt*64+mk*16+hi*4+j, q = q0+w*32+nq*16+lo
    f4_t s[4][2];
#pragma unroll
    for (int mk = 0; mk < 4; ++mk)
#pragma unroll
      for (int nq = 0; nq < 2; ++nq) s[mk][nq] = f4_t{0.f, 0.f, 0.f, 0.f};
#pragma unroll
    for (int kk = 0; kk < 2; ++kk) {
      bf8_t kf[4];
#pragma unroll
      for (int mk = 0; mk < 4; ++mk) {
        int row = mk * 16 + lo;
        int g = (kk * 4 + hi) ^ (row & 7);
        kf[mk] = *(const bf8_t*)&Ks[row * 64 + g * 8];
      }
#pragma unroll
      for (int mk = 0; mk < 4; ++mk)
#pragma unroll
        for (int nq = 0; nq < 2; ++nq)
          s[mk][nq] = MFMA(kf[mk], qf[nq][kk], s[mk][nq]);
    }

    // scale + causal mask (only tiles straddling the diagonal)
    const bool dm = (kt >= 2 * qt);
#pragma unroll
    for (int mk = 0; mk < 4; ++mk)
#pragma unroll
      for (int nq = 0; nq < 2; ++nq)
#pragma unroll
        for (int j = 0; j < 4; ++j) {
          float sv = s[mk][nq][j] * 0.125f;
          if (dm && (kt * 64 + mk * 16 + hi * 4 + j) >
                        (q0 + w * 32 + nq * 16 + lo))
            sv = -1.0e30f;                       // exp -> 0 exactly
          s[mk][nq][j] = sv;
        }

    // online softmax per lane-local q row (16 local vals + 2 shfl steps)
#pragma unroll
    for (int nq = 0; nq < 2; ++nq) {
      float mt = s[0][nq][0];
#pragma unroll
      for (int mk = 0; mk < 4; ++mk)
#pragma unroll
        for (int j = 0; j < 4; ++j) mt = fmaxf(mt, s[mk][nq][j]);
      mt = fmaxf(mt, __shfl_xor(mt, 16));
      mt = fmaxf(mt, __shfl_xor(mt, 32));
      float mnew = fmaxf(m_[nq], mt);
      float f = expf(m_[nq] - mnew);             // 0 on first tile
      float p[16], lt = 0.f, Et = 0.f;
#pragma unroll
      for (int mk = 0; mk < 4; ++mk)
#pragma unroll
        for (int j = 0; j < 4; ++j) {
          float pv = expf(s[mk][nq][j] - mnew);
          p[mk * 4 + j] = pv;
          lt += pv; Et += pv * s[mk][nq][j];     // 0 * -1e30 == -0, no NaN
        }
      lt += __shfl_xor(lt, 16); lt += __shfl_xor(lt, 32);
      Et += __shfl_xor(Et, 16); Et += __shfl_xor(Et, 32);
      l_[nq] = l_[nq] * f + lt;
      E_[nq] = E_[nq] * f + Et;
      m_[nq] = mnew;
#pragma unroll
      for (int md = 0; md < 4; ++md) o[md][nq] *= f;  // same q per vector
      // write P^T row q (packed b64, swizzled)
      int prow = w * 32 + nq * 16 + lo;
#pragma unroll
      for (int mk = 0; mk < 4; ++mk) {
        u32 lo32 = (u32)f2bf(p[mk * 4 + 0]) | ((u32)f2bf(p[mk * 4 + 1]) << 16);
        u32 hi32 = (u32)f2bf(p[mk * 4 + 2]) | ((u32)f2bf(p[mk * 4 + 3]) << 16);
        int g = (mk * 2 + (hi >> 1)) ^ (prow & 7);
        *(uint2*)&Ps[prow * 64 + g * 8 + (hi & 1) * 4] = make_uint2(lo32, hi32);
      }
    }

    // PV (swapped): o[md][nq] += V^T(d x kv) · P^T(kv x q)
#pragma unroll
    for (int kh = 0; kh < 2; ++kh) {
      bf8_t vf[4], pf[2];
#pragma unroll
      for (int md = 0; md < 4; ++md) {
        int row = md * 16 + lo;
        int g = (kh * 4 + hi) ^ (row & 7);
        vf[md] = *(const bf8_t*)&Vt[row * 64 + g * 8];
      }
#pragma unroll
      for (int nq = 0; nq < 2; ++nq) {
        int row = w * 32 + nq * 16 + lo;
        int g = (kh * 4 + hi) ^ (row & 7);
        pf[nq] = *(const bf8_t*)&Ps[row * 64 + g * 8];
      }
#pragma unroll
      for (int md = 0; md < 4; ++md)
#pragma unroll
        for (int nq = 0; nq < 2; ++nq)
          o[md][nq] = MFMA(vf[md], pf[nq], o[md][nq]);
    }
  }

  // ---- epilogue: normalize, transpose through LDS, coalesced bf16 store ----
  __syncthreads();                       // all waves done with main-loop smem
  float* ep = (float*)(smem + w * 8192); // per-wave [32 q][64 d] fp32
  float invl[2];
#pragma unroll
  for (int nq = 0; nq < 2; ++nq) invl[nq] = 1.0f / l_[nq];
#pragma unroll
  for (int md = 0; md < 4; ++md)
#pragma unroll
    for (int nq = 0; nq < 2; ++nq)
#pragma unroll
      for (int j = 0; j < 4; ++j)
        ep[(nq * 16 + lo) * 64 + md * 16 + hi * 4 + j] = o[md][nq][j] * invl[nq];
  __syncthreads();
#pragma unroll
  for (int it = 0; it < 8; ++it) {
    int idx = it * 64 + lane;            // 0..511
    int row = idx >> 4, c4 = idx & 15;
    f4_t v4 = *(const f4_t*)&ep[row * 64 + c4 * 4];
    u32 p0 = (u32)f2bf(v4[0]) | ((u32)f2bf(v4[1]) << 16);
    u32 p1 = (u32)f2bf(v4[2]) | ((u32)f2bf(v4[3]) << 16);
    int t = q0 + w * 32 + row;
    *(uint2*)&Att[((size_t)(b * 2048 + t)) * 1024 + h * 64 + c4 * 4] =
        make_uint2(p0, p1);
  }

  // entropy: H = m + log(l) - E/l per row; one contributor per (lo, nq)
  float hs = 0.f;
  if (hi == 0) {
#pragma unroll
    for (int nq = 0; nq < 2; ++nq)
      hs += m_[nq] + logf(l_[nq]) - E_[nq] * invl[nq];
  }
#pragma unroll
  for (int off = 1; off < 64; off <<= 1) hs += __shfl_xor(hs, off);
  if (lane == 0) wred[w] = hs;
  __syncthreads();
  if (tid == 0)
    atomicAdd(Ent, (wred[0] + wred[1] + wred[2] + wred[3]) * (1.0f / 65536.0f));
}

// ---------------------------------------------------------------------------
// K4: output projection (bf16 MFMA), fp32 output to d_out. grid = (8, 32).
// ---------------------------------------------------------------------------
__global__ __launch_bounds__(256)
void proj_kernel(const u16* __restrict__ Attb, const u16* __restrict__ Wo,
                 const float* __restrict__ bo, float* __restrict__ Out)
{
  __shared__ short As[8192], Bs[8192];
  const int tid = threadIdx.x;
  const int n0 = blockIdx.x * 128;
  const int m0 = blockIdx.y * 128;

  f4_t acc[4][4];
#pragma unroll
  for (int m = 0; m < 4; ++m)
#pragma unroll
    for (int n = 0; n < 4; ++n) acc[m][n] = f4_t{0.f, 0.f, 0.f, 0.f};

  gemm_tile(Attb, Wo, 1024, 1024, m0, n0, 1024, As, Bs, acc, tid);

  const int lane = tid & 63, w = tid >> 6;
  const int lo = lane & 15, hi = lane >> 4;
  const int wr = (w >> 1) * 64, wc = (w & 1) * 64;
#pragma unroll
  for (int n = 0; n < 4; ++n) {
    int col = n0 + wc + n * 16 + lo;
    float bb = bo[col];
#pragma unroll
    for (int m = 0; m < 4; ++m)
#pragma unroll
      for (int j = 0; j < 4; ++j) {
        int row = m0 + wr + m * 16 + hi * 4 + j;
        Out[(size_t)row * 1024 + col] = acc[m][n][j] + bb;
      }
  }
}

// ---------------------------------------------------------------------------
extern "C" void kernel_launch(void* const* d_in, const int* in_sizes, int n_in,
                              void* d_out, int out_size, void* d_ws, size_t ws_size,
                              hipStream_t stream)
{
  const float* x  = (const float*)d_in[0];
  // d_in[1] = causal mask (structure hard-coded)
  const float* wq = (const float*)d_in[2];
  const float* bq = (const float*)d_in[3];
  const float* wk = (const float*)d_in[4];
  const float* bk = (const float*)d_in[5];
  const float* wv = (const float*)d_in[6];
  const float* bv = (const float*)d_in[7];
  const float* wo = (const float*)d_in[8];
  const float* bo = (const float*)d_in[9];

  float* out = (float*)d_out;
  float* ent = out + (size_t)2 * 2048 * 1024;

  char* ws = (char*)d_ws;
  u16* xb   = (u16*)ws;                               // 8 MB  (4096x1024)
  u16* wqb  = (u16*)(ws + 8388608);                   // 2 MB each
  u16* wkb  = (u16*)(ws + 8388608 + 2097152);
  u16* wvb  = (u16*)(ws + 8388608 + 2 * 2097152);
  u16* wob  = (u16*)(ws + 8388608 + 3 * 2097152);
  u16* Qb   = (u16*)(ws + 16777216);                  // 8 MB each, [B,H,T,D]
  u16* Kb   = (u16*)(ws + 16777216 + 8388608);
  u16* Vb   = (u16*)(ws + 16777216 + 2 * 8388608);
  u16* Attb = (u16*)(ws + 16777216 + 3 * 8388608);    // 8 MB, [B,T,C]

  convert_kernel<<<4096, 256, 0, stream>>>(x, wq, wk, wv, wo,
                                           xb, wqb, wkb, wvb, wob, ent);
  qkv_kernel<<<dim3(24, 32), 256, 0, stream>>>(xb, wqb, wkb, wvb,
                                               bq, bk, bv, Qb, Kb, Vb);
  attn_kernel<<<dim3(16, 32), 256, 0, stream>>>(Qb, Kb, Vb, Attb, ent);
  proj_kernel<<<dim3(8, 32), 256, 0, stream>>>(Attb, wob, bo, out);
}

// Round 3
// 309.571 us; speedup vs baseline: 6.0796x; 1.0233x over previous
//
#include <hip/hip_runtime.h>
#include <math.h>

// B=2, T=2048, C=1024, H=16, D=64
typedef short bf8_t __attribute__((ext_vector_type(8)));   // 8 bf16 (4 VGPR)
typedef float f4_t  __attribute__((ext_vector_type(4)));
typedef unsigned int u32;
typedef unsigned short u16;

#define MFMA(a,b,c) __builtin_amdgcn_mfma_f32_16x16x32_bf16((a),(b),(c),0,0,0)

__device__ __forceinline__ void gload16(const void* g, void* l) {
  __builtin_amdgcn_global_load_lds(
      (const __attribute__((address_space(1))) void*)g,
      (__attribute__((address_space(3))) void*)l, 16, 0, 0);
}

__device__ __forceinline__ u16 f2bf(float f) {   // RNE f32->bf16
  u32 u = __float_as_uint(f);
  u += 0x7fff + ((u >> 16) & 1);
  return (u16)(u >> 16);
}

// ---------------------------------------------------------------------------
// 128x128 bf16-MFMA GEMM tile (unchanged from round 2): acc += A * B^T.
// ---------------------------------------------------------------------------
__device__ __forceinline__ void gemm_tile(
    const u16* __restrict__ A, const u16* __restrict__ Bm,
    int lda, int ldb, int m0, int n0, int K,
    short* As, short* Bs, f4_t acc[4][4], int tid)
{
  const int lane = tid & 63, w = tid >> 6;
  const int lo = lane & 15, hi = lane >> 4;
  const int wr = (w >> 1) * 64, wc = (w & 1) * 64;
  for (int k0 = 0; k0 < K; k0 += 64) {
    __syncthreads();
#pragma unroll
    for (int iss = 0; iss < 4; ++iss) {
      int bb = iss * 4096 + tid * 16;
      int row = bb >> 7;
      int lg = ((bb >> 4) & 7) ^ (row & 7);
      gload16(A  + (size_t)(m0 + row) * lda + k0 + lg * 8,
              (char*)As + iss * 4096 + w * 1024);
      gload16(Bm + (size_t)(n0 + row) * ldb + k0 + lg * 8,
              (char*)Bs + iss * 4096 + w * 1024);
    }
    __syncthreads();
#pragma unroll
    for (int kk = 0; kk < 2; ++kk) {
      bf8_t af[4], bfr[4];
#pragma unroll
      for (int m = 0; m < 4; ++m) {
        int row = wr + m * 16 + lo;
        int g = (kk * 4 + hi) ^ (row & 7);
        af[m] = *(const bf8_t*)&As[row * 64 + g * 8];
      }
#pragma unroll
      for (int n = 0; n < 4; ++n) {
        int row = wc + n * 16 + lo;
        int g = (kk * 4 + hi) ^ (row & 7);
        bfr[n] = *(const bf8_t*)&Bs[row * 64 + g * 8];
      }
#pragma unroll
      for (int m = 0; m < 4; ++m)
#pragma unroll
        for (int n = 0; n < 4; ++n)
          acc[m][n] = MFMA(af[m], bfr[n], acc[m][n]);
    }
  }
}

// ---------------------------------------------------------------------------
// K1: fp32 -> bf16 conversion of x and weights; zero entropy scalar.
// ---------------------------------------------------------------------------
__global__ __launch_bounds__(256)
void convert_kernel(const float* __restrict__ x,  const float* __restrict__ wq,
                    const float* __restrict__ wk, const float* __restrict__ wv,
                    const float* __restrict__ wo,
                    u16* xb, u16* wqb, u16* wkb, u16* wvb, u16* wob, float* ent)
{
  size_t i = (size_t)blockIdx.x * 256 + threadIdx.x;
  if (blockIdx.x == 0 && threadIdx.x == 0) *ent = 0.f;
  const float* src; u16* dst; size_t off;
  if (i < 524288) { src = x; dst = xb; off = i; }
  else {
    size_t r = i - 524288;
    int sel = (int)(r >> 17);
    off = r & 131071;
    src = sel == 0 ? wq : sel == 1 ? wk : sel == 2 ? wv : wo;
    dst = sel == 0 ? wqb : sel == 1 ? wkb : sel == 2 ? wvb : wob;
  }
  f4_t a = *(const f4_t*)&src[off * 8];
  f4_t c = *(const f4_t*)&src[off * 8 + 4];
  u16 t[8] = {f2bf(a[0]), f2bf(a[1]), f2bf(a[2]), f2bf(a[3]),
              f2bf(c[0]), f2bf(c[1]), f2bf(c[2]), f2bf(c[3])};
  *(uint4*)&dst[off * 8] = *(const uint4*)t;
}

// ---------------------------------------------------------------------------
// K2: fused QKV projection. Q,K -> [B,H,T,D]; V -> TRANSPOSED [B,H,D,T]
// so attention's PV A-operand is a contiguous 16B load from L2.
// ---------------------------------------------------------------------------
__global__ __launch_bounds__(256)
void qkv_kernel(const u16* __restrict__ X, const u16* __restrict__ Wq,
                const u16* __restrict__ Wk, const u16* __restrict__ Wv,
                const float* __restrict__ bq, const float* __restrict__ bk,
                const float* __restrict__ bv,
                u16* Qo, u16* Ko, u16* Vto)
{
  __shared__ short As[8192], Bs[8192];
  const int tid = threadIdx.x;
  const int nb = blockIdx.x;
  const int which = nb >> 3;
  const int n0 = (nb & 7) * 128;
  const int m0 = blockIdx.y * 128;
  const u16* W    = which == 0 ? Wq : which == 1 ? Wk : Wv;
  const float* bias = which == 0 ? bq : which == 1 ? bk : bv;

  f4_t acc[4][4];
#pragma unroll
  for (int m = 0; m < 4; ++m)
#pragma unroll
    for (int n = 0; n < 4; ++n) acc[m][n] = f4_t{0.f, 0.f, 0.f, 0.f};

  gemm_tile(X, W, 1024, 1024, m0, n0, 1024, As, Bs, acc, tid);

  const int lane = tid & 63, w = tid >> 6;
  const int lo = lane & 15, hi = lane >> 4;
  const int wr = (w >> 1) * 64, wc = (w & 1) * 64;
#pragma unroll
  for (int n = 0; n < 4; ++n) {
    int col = n0 + wc + n * 16 + lo;
    float bb = bias[col];
    int hh = col >> 6, d = col & 63;
#pragma unroll
    for (int m = 0; m < 4; ++m)
#pragma unroll
      for (int j = 0; j < 4; ++j) {
        int row = m0 + wr + m * 16 + hi * 4 + j;
        int bidx = row >> 11, t = row & 2047;
        u16 val = f2bf(acc[m][n][j] + bb);
        if (which < 2) {
          u16* Out = which == 0 ? Qo : Ko;
          Out[(((size_t)bidx * 16 + hh) * 2048 + t) * 64 + d] = val;
        } else {
          Vto[(((size_t)bidx * 16 + hh) * 64 + d) * 2048 + t] = val;
        }
      }
  }
}

// ---------------------------------------------------------------------------
// K3: causal flash attention, barrier-free. Each wave runs one 16-row phase:
// direct-from-L2 K and V^T fragments, swapped QK^T (mfma(K,Q)) and swapped
// PV (mfma(V^T, P^T)) so softmax state is lane-local (q = q0 + lane&15).
// P round-trips a per-wave 2KB swizzled LDS strip (same-wave, no barrier).
// ---------------------------------------------------------------------------
__device__ __forceinline__ float attn_phase(
    const u16* __restrict__ Qb, const u16* __restrict__ Kb,
    const u16* __restrict__ Vtb, u16* __restrict__ Attp,
    short* __restrict__ Pw, int q0, int ntile, int lo, int hi)
{
  // Q fragments (B-operand): n = q0+lo, k = d
  bf8_t qf[2];
#pragma unroll
  for (int kk = 0; kk < 2; ++kk)
    qf[kk] = *(const bf8_t*)&Qb[(size_t)(q0 + lo) * 64 + kk * 32 + hi * 8];

  f4_t o[4];
#pragma unroll
  for (int md = 0; md < 4; ++md) o[md] = f4_t{0.f, 0.f, 0.f, 0.f};
  float m_ = -3.0e38f, l_ = 0.f, E_ = 0.f;
  const int wq16 = q0 & 63;                 // w*16: row offset inside q-tile

  for (int kt = 0; kt < ntile; ++kt) {
    const u16* Kt = Kb + (size_t)kt * (64 * 64);
    bf8_t kf[4][2], vf[4][2];
#pragma unroll
    for (int mk = 0; mk < 4; ++mk)
#pragma unroll
      for (int kk = 0; kk < 2; ++kk)
        kf[mk][kk] = *(const bf8_t*)&Kt[(mk * 16 + lo) * 64 + kk * 32 + hi * 8];
#pragma unroll
    for (int md = 0; md < 4; ++md)
#pragma unroll
      for (int kh = 0; kh < 2; ++kh)
        vf[md][kh] = *(const bf8_t*)
            &Vtb[(size_t)(md * 16 + lo) * 2048 + kt * 64 + kh * 32 + hi * 8];

    // S' = K . Q^T : s[mk][j] at kv = kt*64 + mk*16 + hi*4 + j, q = q0 + lo
    f4_t s[4];
#pragma unroll
    for (int mk = 0; mk < 4; ++mk) s[mk] = f4_t{0.f, 0.f, 0.f, 0.f};
#pragma unroll
    for (int kk = 0; kk < 2; ++kk)
#pragma unroll
      for (int mk = 0; mk < 4; ++mk)
        s[mk] = MFMA(kf[mk][kk], qf[kk], s[mk]);

    // scale + causal mask (diagonal tile is always the last one)
    const bool dm = (kt == ntile - 1);
#pragma unroll
    for (int mk = 0; mk < 4; ++mk)
#pragma unroll
      for (int jj = 0; jj < 4; ++jj) {
        float sv = s[mk][jj] * 0.125f;
        if (dm && (mk * 16 + hi * 4 + jj) > (wq16 + lo)) sv = -1.0e30f;
        s[mk][jj] = sv;
      }

    // online softmax for the lane-local q row (16 vals + 2 shfl steps)
    float mt = s[0][0];
#pragma unroll
    for (int mk = 0; mk < 4; ++mk)
#pragma unroll
      for (int jj = 0; jj < 4; ++jj) mt = fmaxf(mt, s[mk][jj]);
    mt = fmaxf(mt, __shfl_xor(mt, 16));
    mt = fmaxf(mt, __shfl_xor(mt, 32));
    float mnew = fmaxf(m_, mt);
    float f = __expf(m_ - mnew);            // 0 on first tile
    float p[16], lt = 0.f, Et = 0.f;
#pragma unroll
    for (int mk = 0; mk < 4; ++mk)
#pragma unroll
      for (int jj = 0; jj < 4; ++jj) {
        float pv = __expf(s[mk][jj] - mnew);
        p[mk * 4 + jj] = pv;
        lt += pv; Et += pv * s[mk][jj];     // 0 * -1e30 == -0, no NaN
      }
    lt += __shfl_xor(lt, 16); lt += __shfl_xor(lt, 32);
    Et += __shfl_xor(Et, 16); Et += __shfl_xor(Et, 32);
    l_ = l_ * f + lt; E_ = E_ * f + Et; m_ = mnew;
#pragma unroll
    for (int md = 0; md < 4; ++md) o[md] *= f;

    // P^T row (q=lo) -> per-wave LDS strip [16][64], 16B-granule XOR swizzle
#pragma unroll
    for (int mk = 0; mk < 4; ++mk) {
      u32 l32 = (u32)f2bf(p[mk * 4 + 0]) | ((u32)f2bf(p[mk * 4 + 1]) << 16);
      u32 h32 = (u32)f2bf(p[mk * 4 + 2]) | ((u32)f2bf(p[mk * 4 + 3]) << 16);
      int g = (mk * 2 + (hi >> 1)) ^ (lo & 7);
      *(uint2*)&Pw[lo * 64 + g * 8 + (hi & 1) * 4] = make_uint2(l32, h32);
    }

    // PV (swapped): o[md] += V^T(d x kv) . P^T(kv x q)
#pragma unroll
    for (int kh = 0; kh < 2; ++kh) {
      int g = (kh * 4 + hi) ^ (lo & 7);
      bf8_t pf = *(const bf8_t*)&Pw[lo * 64 + g * 8];
#pragma unroll
      for (int md = 0; md < 4; ++md)
        o[md] = MFMA(vf[md][kh], pf, o[md]);
    }
  }

  // epilogue: normalize + direct bf16 store (8B per lane per md)
  float invl = 1.0f / l_;
#pragma unroll
  for (int md = 0; md < 4; ++md) {
    u32 w0 = (u32)f2bf(o[md][0] * invl) | ((u32)f2bf(o[md][1] * invl) << 16);
    u32 w1 = (u32)f2bf(o[md][2] * invl) | ((u32)f2bf(o[md][3] * invl) << 16);
    *(uint2*)&Attp[(size_t)(q0 + lo) * 1024 + md * 16 + hi * 4] =
        make_uint2(w0, w1);
  }
  // entropy: H = m + log(l) - E/l ; one contributor per row (hi==0)
  return (hi == 0) ? (m_ + __logf(l_) - E_ * invl) : 0.f;
}

__global__ __launch_bounds__(256)
void attn_kernel(const u16* __restrict__ Qg, const u16* __restrict__ Kg,
                 const u16* __restrict__ Vtg, u16* __restrict__ Att,
                 float* __restrict__ Ent)
{
  __shared__ short Ps[4][1024];            // per-wave [16 q][64 kv]
  const int tid = threadIdx.x, lane = tid & 63, w = tid >> 6;
  const int lo = lane & 15, hi = lane >> 4;
  // XCD-friendly mapping: round-robin (n%8) keeps only 4 bh values per XCD
  const int n = blockIdx.x;
  const int bh = (n & 7) * 4 + ((n >> 3) & 3);
  const int jp = n >> 5;                   // 0..15 -> tiles {jp, 31-jp}
  const int b = bh >> 4, h = bh & 15;
  const u16* Qb  = Qg  + (size_t)bh * (2048 * 64);
  const u16* Kb  = Kg  + (size_t)bh * (2048 * 64);
  const u16* Vtb = Vtg + (size_t)bh * (64 * 2048);
  u16* Attp = Att + (size_t)b * (2048 * 1024) + h * 64;
  short* Pw = Ps[w];

  // two balanced phases: every wave does (jp+1) + (32-jp) = 33 K-tiles
  float hs = 0.f;
  hs += attn_phase(Qb, Kb, Vtb, Attp, Pw, jp * 64 + w * 16, jp + 1, lo, hi);
  hs += attn_phase(Qb, Kb, Vtb, Attp, Pw, (31 - jp) * 64 + w * 16, 32 - jp,
                   lo, hi);

#pragma unroll
  for (int off = 1; off < 64; off <<= 1) hs += __shfl_xor(hs, off);
  if (lane == 0) atomicAdd(Ent, hs * (1.0f / 65536.0f));
}

// ---------------------------------------------------------------------------
// K4: output projection (bf16 MFMA), fp32 output. grid = (8, 32).
// ---------------------------------------------------------------------------
__global__ __launch_bounds__(256)
void proj_kernel(const u16* __restrict__ Attb, const u16* __restrict__ Wo,
                 const float* __restrict__ bo, float* __restrict__ Out)
{
  __shared__ short As[8192], Bs[8192];
  const int tid = threadIdx.x;
  const int n0 = blockIdx.x * 128;
  const int m0 = blockIdx.y * 128;

  f4_t acc[4][4];
#pragma unroll
  for (int m = 0; m < 4; ++m)
#pragma unroll
    for (int n = 0; n < 4; ++n) acc[m][n] = f4_t{0.f, 0.f, 0.f, 0.f};

  gemm_tile(Attb, Wo, 1024, 1024, m0, n0, 1024, As, Bs, acc, tid);

  const int lane = tid & 63, w = tid >> 6;
  const int lo = lane & 15, hi = lane >> 4;
  const int wr = (w >> 1) * 64, wc = (w & 1) * 64;
#pragma unroll
  for (int n = 0; n < 4; ++n) {
    int col = n0 + wc + n * 16 + lo;
    float bb = bo[col];
#pragma unroll
    for (int m = 0; m < 4; ++m)
#pragma unroll
      for (int j = 0; j < 4; ++j) {
        int row = m0 + wr + m * 16 + hi * 4 + j;
        Out[(size_t)row * 1024 + col] = acc[m][n][j] + bb;
      }
  }
}

// ---------------------------------------------------------------------------
extern "C" void kernel_launch(void* const* d_in, const int* in_sizes, int n_in,
                              void* d_out, int out_size, void* d_ws, size_t ws_size,
                              hipStream_t stream)
{
  const float* x  = (const float*)d_in[0];
  // d_in[1] = causal mask (structure hard-coded)
  const float* wq = (const float*)d_in[2];
  const float* bq = (const float*)d_in[3];
  const float* wk = (const float*)d_in[4];
  const float* bk = (const float*)d_in[5];
  const float* wv = (const float*)d_in[6];
  const float* bv = (const float*)d_in[7];
  const float* wo = (const float*)d_in[8];
  const float* bo = (const float*)d_in[9];

  float* out = (float*)d_out;
  float* ent = out + (size_t)2 * 2048 * 1024;

  char* ws = (char*)d_ws;
  u16* xb   = (u16*)ws;                               // 8 MB  (4096x1024)
  u16* wqb  = (u16*)(ws + 8388608);                   // 2 MB each
  u16* wkb  = (u16*)(ws + 8388608 + 2097152);
  u16* wvb  = (u16*)(ws + 8388608 + 2 * 2097152);
  u16* wob  = (u16*)(ws + 8388608 + 3 * 2097152);
  u16* Qb   = (u16*)(ws + 16777216);                  // 8 MB, [B,H,T,D]
  u16* Kb   = (u16*)(ws + 16777216 + 8388608);        // 8 MB, [B,H,T,D]
  u16* Vtb  = (u16*)(ws + 16777216 + 2 * 8388608);    // 8 MB, [B,H,D,T]
  u16* Attb = (u16*)(ws + 16777216 + 3 * 8388608);    // 8 MB, [B,T,C]

  convert_kernel<<<4096, 256, 0, stream>>>(x, wq, wk, wv, wo,
                                           xb, wqb, wkb, wvb, wob, ent);
  qkv_kernel<<<dim3(24, 32), 256, 0, stream>>>(xb, wqb, wkb, wvb,
                                               bq, bk, bv, Qb, Kb, Vtb);
  attn_kernel<<<512, 256, 0, stream>>>(Qb, Kb, Vtb, Attb, ent);
  proj_kernel<<<dim3(8, 32), 256, 0, stream>>>(Attb, wob, bo, out);
}